// Round 2
// baseline (128.382 us; speedup 1.0000x reference)
//
#include <hip/hip_runtime.h>
#include <cstdint>
#include <cstddef>

// Problem constants: B=8, C=64, H=W=32 -> N=8192 nodes, K=9 neighbors, OUT=64.
// Batches (from linspace truncation): k = [1024k,1024(k+1)) for k<=6,
// batch 7 = [7168,8190], batch 8 = {8191} (singleton -> mean = self).

// ---------------------------------------------------------------------------
// K1: transpose x (8,64,32,32) -> xf[8192][64], and sq[n] = sum_c xf[n][c]^2
// ---------------------------------------------------------------------------
__global__ __launch_bounds__(256) void k_transpose_sq(const float* __restrict__ x,
                                                      float* __restrict__ xf,
                                                      float* __restrict__ sq) {
  __shared__ float tile[64][65];
  int blk = blockIdx.x;           // 128 blocks: 8 b x 16 hw-tiles
  int b = blk >> 4;
  int hw0 = (blk & 15) << 6;
  int t = threadIdx.x;
  int lane_hw = t & 63;
  int c_base = t >> 6;            // 0..3
#pragma unroll
  for (int i = 0; i < 16; ++i) {
    int c = c_base + (i << 2);
    tile[c][lane_hw] = x[((b * 64 + c) << 10) + hw0 + lane_hw];
  }
  __syncthreads();
  int c_out = t & 63;
  int hw_base = t >> 6;
#pragma unroll
  for (int i = 0; i < 16; ++i) {
    int hw = hw_base + (i << 2);
    xf[(size_t)(((b << 10) + hw0 + hw) << 6) + c_out] = tile[c_out][hw];
  }
  if (t < 64) {
    float s = 0.f;
#pragma unroll
    for (int c = 0; c < 64; ++c) { float v = tile[c][t]; s += v * v; }
    sq[(b << 10) + hw0 + t] = s;
  }
}

// ---------------------------------------------------------------------------
// K3: distance GEMM, rewritten.
// D[i][jj] = sq[i] + sq[j0+jj] - 2*dot(xf[i], xf[j0+jj]), jj in [0,1024).
// 128x128 tile per block; K=64 staged ONCE as float4 q-planes (q = k/4):
//   LDS f4-index = (q<<7) | ((m ^ (q&7)))   [XOR swizzle -> 2-way banks]
// Thread (tx,ty) owns rows {ty+16r} cols {tx+16cc} (strided) -> all fragment
// loads are single aligned ds_read_b128; 16 reads per 256 FMAs.
// ---------------------------------------------------------------------------
__global__ __launch_bounds__(256) void k_dist(const float* __restrict__ xf,
                                              const float* __restrict__ sq,
                                              float* __restrict__ D) {
  __shared__ float4 As4[2048];    // 32 KB: [q:16][m:128] swizzled
  __shared__ float4 Bs4[2048];    // 32 KB
  int i0 = blockIdx.y << 7;       // 0..8064
  int jj0 = blockIdx.x << 7;      // 0..896
  int s = (i0 >= 7168) ? 7168 : (i0 & ~1023);
  int j0 = s + jj0;
  int t = threadIdx.x;
  int tx = t & 15, ty = t >> 4;

  // stage A and B tiles: unit u = t + 256*i; q = u&15 (coalesced), m = u>>4
#pragma unroll
  for (int i = 0; i < 8; ++i) {
    int u = t + (i << 8);
    int q = u & 15, m = u >> 4;
    int dst = (q << 7) | (m ^ (q & 7));
    As4[dst] = *(const float4*)&xf[((size_t)(i0 + m) << 6) + (q << 2)];
    Bs4[dst] = *(const float4*)&xf[((size_t)(j0 + m) << 6) + (q << 2)];
  }
  __syncthreads();

  float acc[8][8];
#pragma unroll
  for (int r = 0; r < 8; ++r)
#pragma unroll
    for (int c = 0; c < 8; ++c) acc[r][c] = 0.f;

#pragma unroll 1
  for (int q = 0; q < 16; ++q) {
    int base = q << 7;
    int sw = q & 7;
    float4 a[8], b[8];
#pragma unroll
    for (int r = 0; r < 8; ++r) a[r] = As4[base | ((ty + (r << 4)) ^ sw)];
#pragma unroll
    for (int c = 0; c < 8; ++c) b[c] = Bs4[base | ((tx + (c << 4)) ^ sw)];
#pragma unroll
    for (int r = 0; r < 8; ++r)
#pragma unroll
      for (int c = 0; c < 8; ++c) {
        float v = acc[r][c];
        v = fmaf(a[r].x, b[c].x, v);
        v = fmaf(a[r].y, b[c].y, v);
        v = fmaf(a[r].z, b[c].z, v);
        v = fmaf(a[r].w, b[c].w, v);
        acc[r][c] = v;
      }
  }

  float sqi[8], sqj[8];
#pragma unroll
  for (int r = 0; r < 8; ++r) sqi[r] = sq[i0 + ty + (r << 4)];
#pragma unroll
  for (int c = 0; c < 8; ++c) sqj[c] = sq[j0 + tx + (c << 4)];
#pragma unroll
  for (int r = 0; r < 8; ++r) {
    size_t rowbase = ((size_t)(i0 + ty + (r << 4)) << 10) + jj0 + tx;
#pragma unroll
    for (int c = 0; c < 8; ++c)
      D[rowbase + (c << 4)] = sqi[r] + sqj[c] - 2.f * acc[r][c];
  }
}

// ---------------------------------------------------------------------------
// K4: exact top-9 per row (one wave per row). Key = (orderable-dist << 32)|jj
// -> min picks smallest dist, ties -> smallest index (matches lax.top_k).
// ---------------------------------------------------------------------------
__global__ __launch_bounds__(256) void k_select(const float* __restrict__ D,
                                                int* __restrict__ idxO) {
  int t = threadIdx.x;
  int lane = t & 63;
  int i = (blockIdx.x << 2) + (t >> 6);
  if (i == 8191) {                 // singleton batch: neighbor = self
    if (lane == 0) idxO[i * 9] = 8191;
    return;
  }
  int s = (i >= 7168) ? 7168 : (i & ~1023);
  bool mlast = (i >= 7168);        // rows of batch 7 must exclude j=8191
  const float* drow = D + ((size_t)i << 10);
  unsigned long long cand[16];
#pragma unroll
  for (int q = 0; q < 16; ++q) {
    int jj = lane + (q << 6);
    float d = drow[jj];
    unsigned u = __float_as_uint(d);
    u = (u & 0x80000000u) ? ~u : (u | 0x80000000u);
    unsigned long long key = ((unsigned long long)u << 32) | (unsigned)jj;
    if (mlast && jj == 1023) key = ~0ull;
    cand[q] = key;
  }
#pragma unroll
  for (int kk = 0; kk < 9; ++kk) {
    unsigned long long m = cand[0];
#pragma unroll
    for (int q = 1; q < 16; ++q) m = (cand[q] < m) ? cand[q] : m;
#pragma unroll
    for (int off = 32; off > 0; off >>= 1) {
      unsigned hi = __shfl_xor((unsigned)(m >> 32), off, 64);
      unsigned lo = __shfl_xor((unsigned)(m & 0xffffffffu), off, 64);
      unsigned long long o = ((unsigned long long)hi << 32) | lo;
      m = (o < m) ? o : m;
    }
    if (lane == 0) idxO[i * 9 + kk] = s + (int)(m & 0xffffffffu);
#pragma unroll
    for (int q = 0; q < 16; ++q) if (cand[q] == m) cand[q] = ~0ull;
  }
}

// ---------------------------------------------------------------------------
// K5: mean of neighbors + out = mean@Wl^T + bl + xf@Wr^T.
// ---------------------------------------------------------------------------
__global__ __launch_bounds__(256) void k_out(const float* __restrict__ xf,
                                             const int* __restrict__ idxO,
                                             const float* __restrict__ Wl,
                                             const float* __restrict__ bl,
                                             const float* __restrict__ Wr,
                                             float* __restrict__ out) {
  __shared__ float WsL[64][65];
  __shared__ float WsR[64][65];
  int t = threadIdx.x;
#pragma unroll
  for (int i = 0; i < 16; ++i) {
    int lin = t + (i << 8);
    WsL[lin >> 6][lin & 63] = Wl[lin];
    WsR[lin >> 6][lin & 63] = Wr[lin];
  }
  __syncthreads();
  int lane = t & 63;
  float wl[64], wr[64];
#pragma unroll
  for (int c = 0; c < 64; ++c) { wl[c] = WsL[lane][c]; wr[c] = WsR[lane][c]; }
  float bias = bl[lane];
  int wave = t >> 6;
  int n0 = (blockIdx.x << 4) + (wave << 2);   // 4 nodes per wave
  for (int nn = 0; nn < 4; ++nn) {
    int n = n0 + nn;
    int cnt = (n == 8191) ? 1 : 9;            // wave-uniform
    float msum = 0.f;
    for (int k = 0; k < cnt; ++k) {
      int j = idxO[n * 9 + k];                // uniform across wave
      msum += xf[((size_t)j << 6) + lane];    // coalesced gather
    }
    float mean = msum / (float)cnt;           // lane c = feature c
    float xr = xf[((size_t)n << 6) + lane];
    float acc = bias;
#pragma unroll
    for (int c = 0; c < 64; ++c) {
      float mc = __int_as_float(__builtin_amdgcn_readlane(__float_as_int(mean), c));
      float xc = __int_as_float(__builtin_amdgcn_readlane(__float_as_int(xr), c));
      acc += mc * wl[c];
      acc += xc * wr[c];
    }
    out[((size_t)n << 6) + lane] = acc;
  }
}

// ---------------------------------------------------------------------------
extern "C" void kernel_launch(void* const* d_in, const int* in_sizes, int n_in,
                              void* d_out, int out_size, void* d_ws, size_t ws_size,
                              hipStream_t stream) {
  const float* x  = (const float*)d_in[0];   // (8,64,32,32)
  const float* Wl = (const float*)d_in[1];   // (64,64)
  const float* bl = (const float*)d_in[2];   // (64,)
  const float* Wr = (const float*)d_in[3];   // (64,64)
  float* out = (float*)d_out;                // (8192,64)

  char* ws = (char*)d_ws;
  float* xf  = (float*)(ws);                                   // 2,097,152 B
  float* sq  = (float*)(ws + 2097152);                         //    32,768 B
  int*   idx = (int*)  (ws + 2097152 + 32768);                 //   294,912 B
  float* D   = (float*)(ws + 2097152 + 32768 + 294912);        // 33,554,432 B

  k_transpose_sq<<<128, 256, 0, stream>>>(x, xf, sq);
  k_dist<<<dim3(8, 64), 256, 0, stream>>>(xf, sq, D);
  k_select<<<2048, 256, 0, stream>>>(D, idx);
  k_out<<<512, 256, 0, stream>>>(xf, idx, Wl, bl, Wr, out);
}